// Round 1
// baseline (857.959 us; speedup 1.0000x reference)
//
#include <hip/hip_runtime.h>
#include <math.h>

// Problem constants
#define BB_ 4
#define NN_ 256
#define DD_ 256
#define HH_ 8
#define DHH_ 32

// ---------------------------------------------------------------------------
// K0: transpose W (256x256) -> Wt so row-per-thread consumers read coalesced
// ---------------------------------------------------------------------------
__global__ __launch_bounds__(256) void k_transpose(const float* __restrict__ W,
                                                   float* __restrict__ Wt) {
    int d = blockIdx.x;   // row of W
    int k = threadIdx.x;  // col of W
    Wt[k * 256 + d] = W[d * 256 + k];
}

// ---------------------------------------------------------------------------
// K1: node projection  np[row][d] = bias[d] + sum_k nodes[row][k] * W[d][k]
//     (uses Wt for coalesced reads: Wt[k][d])
// ---------------------------------------------------------------------------
__global__ __launch_bounds__(256) void k_node_proj(const float* __restrict__ nodes,
                                                   const float* __restrict__ Wt,
                                                   const float* __restrict__ bias,
                                                   float* __restrict__ np_) {
    int row = blockIdx.x;   // b*256 + n  (1024 rows)
    int d = threadIdx.x;
    __shared__ float xl[256];
    xl[d] = nodes[row * 256 + d];
    __syncthreads();
    float acc = bias[d];
#pragma unroll 8
    for (int k = 0; k < 256; ++k) acc = fmaf(xl[k], Wt[k * 256 + d], acc);
    np_[row * 256 + d] = acc;
}

// ---------------------------------------------------------------------------
// K2 (heavy): per edge (b,i,j): p = W e + bias; per head h:
//   score = (p+np_i)·(p+np_j) over the head's 32 dims
//   attn_raw[b,h,i,j] = 10*tanh(score/sqrt(32))
// Tile: 64 edges (same b,i; consecutive j) x 256 outputs.
// Thread (gy,gx): gy=t>>5 edge-octet, gx=t&31; outputs d = c*32+gx (head==c).
// ---------------------------------------------------------------------------
__global__ __launch_bounds__(256) void k_edge_scores(const float* __restrict__ edges,
                                                     const float* __restrict__ W,
                                                     const float* __restrict__ bias,
                                                     const float* __restrict__ np_,
                                                     float* __restrict__ attn) {
    __shared__ float El[64 * 36];    // 64 edges x 32k, pad 36
    __shared__ float Wl[256 * 36];   // 256 d x 32k, pad 36
    __shared__ float npi[256];

    const int t = threadIdx.x;
    const int gy = t >> 5;
    const int gx = t & 31;
    const int m0 = blockIdx.x * 64;        // first edge index of tile
    const int bb = m0 >> 16;               // batch
    const int ii = (m0 >> 8) & 255;        // i node
    const int j0 = m0 & 255;               // first j of tile (0,64,128,192)

    if (t < 64) {
        ((float4*)npi)[t] = ((const float4*)(np_ + (bb * 256 + ii) * 256))[t];
    }

    float acc[8][8];
#pragma unroll
    for (int e = 0; e < 8; ++e)
#pragma unroll
        for (int c = 0; c < 8; ++c) acc[e][c] = 0.f;

    const float* eg = edges + (size_t)m0 * 256;

    for (int kc = 0; kc < 8; ++kc) {
        __syncthreads();
        // stage E tile: 64 rows x 32 k = 512 float4
#pragma unroll
        for (int s = 0; s < 2; ++s) {
            int idx = t + s * 256;
            int row = idx >> 3, q = idx & 7;
            float4 v = *(const float4*)(eg + row * 256 + kc * 32 + q * 4);
            *(float4*)(El + row * 36 + q * 4) = v;
        }
        // stage W tile: 256 rows x 32 k = 2048 float4
#pragma unroll
        for (int s = 0; s < 8; ++s) {
            int idx = t + s * 256;
            int d = idx >> 3, q = idx & 7;
            float4 v = *(const float4*)(W + d * 256 + kc * 32 + q * 4);
            *(float4*)(Wl + d * 36 + q * 4) = v;
        }
        __syncthreads();
#pragma unroll
        for (int k = 0; k < 32; k += 4) {
            float4 rE[8], rW[8];
#pragma unroll
            for (int e = 0; e < 8; ++e)
                rE[e] = *(const float4*)(El + (gy * 8 + e) * 36 + k);
#pragma unroll
            for (int c = 0; c < 8; ++c)
                rW[c] = *(const float4*)(Wl + (c * 32 + gx) * 36 + k);
#pragma unroll
            for (int e = 0; e < 8; ++e)
#pragma unroll
                for (int c = 0; c < 8; ++c) {
                    acc[e][c] = fmaf(rE[e].x, rW[c].x, acc[e][c]);
                    acc[e][c] = fmaf(rE[e].y, rW[c].y, acc[e][c]);
                    acc[e][c] = fmaf(rE[e].z, rW[c].z, acc[e][c]);
                    acc[e][c] = fmaf(rE[e].w, rW[c].w, acc[e][c]);
                }
        }
    }

    // epilogue
    float bv[8];
#pragma unroll
    for (int c = 0; c < 8; ++c) bv[c] = bias[c * 32 + gx];

    const float isq = 0.17677669529663687f;  // 1/sqrt(32)
#pragma unroll
    for (int e = 0; e < 8; ++e) {
        int el = gy * 8 + e;
        int j = j0 + el;
        const float* npj = np_ + (bb * 256 + j) * 256;
        float s[8];
#pragma unroll
        for (int c = 0; c < 8; ++c) {
            int d = c * 32 + gx;
            float pe = acc[e][c] + bv[c];
            float qv = pe + npi[d];
            float kv = pe + npj[d];
            s[c] = qv * kv;
        }
        // butterfly reduce over the 32 gx lanes (stay within 32-lane half)
#pragma unroll
        for (int m = 1; m < 32; m <<= 1) {
#pragma unroll
            for (int c = 0; c < 8; ++c) s[c] += __shfl_xor(s[c], m, 64);
        }
        if (gx < 8) {
            float val = s[0];
#pragma unroll
            for (int c = 1; c < 8; ++c)
                if (gx == c) val = s[c];
            float sc = 10.f * tanhf(val * isq);
            attn[(((bb * 8 + gx) * 256 + ii) << 8) + j] = sc;
        }
    }
}

// ---------------------------------------------------------------------------
// K3: in-place softmax over last axis j. One wave per (b,h,i) row of 256.
// ---------------------------------------------------------------------------
__global__ __launch_bounds__(256) void k_softmax(float* __restrict__ attn) {
    int row = (blockIdx.x * 256 + threadIdx.x) >> 6;  // 0..8191
    int lane = threadIdx.x & 63;
    float4* rowp = (float4*)(attn + (size_t)row * 256);
    float4 v = rowp[lane];
    float m = fmaxf(fmaxf(v.x, v.y), fmaxf(v.z, v.w));
#pragma unroll
    for (int s = 1; s < 64; s <<= 1) m = fmaxf(m, __shfl_xor(m, s, 64));
    v.x = expf(v.x - m);
    v.y = expf(v.y - m);
    v.z = expf(v.z - m);
    v.w = expf(v.w - m);
    float sum = v.x + v.y + v.z + v.w;
#pragma unroll
    for (int s = 1; s < 64; s <<= 1) sum += __shfl_xor(sum, s, 64);
    float inv = 1.f / sum;
    v.x *= inv; v.y *= inv; v.z *= inv; v.w *= inv;
    rowp[lane] = v;
}

// ---------------------------------------------------------------------------
// K4: out1[b,i,d] = sum_j attn[b,h(d),i,j] * np[b,j,d]; then out = proj(out1)
// fused in one block per (b,i).
// ---------------------------------------------------------------------------
__global__ __launch_bounds__(256) void k_out(const float* __restrict__ attn,
                                             const float* __restrict__ np_,
                                             const float* __restrict__ Wt,
                                             const float* __restrict__ bias,
                                             float* __restrict__ out) {
    int bi = blockIdx.x;   // b*256 + i
    int bb = bi >> 8, ii = bi & 255;
    int d = threadIdx.x;
    __shared__ float at[8 * 256];
    __shared__ float xl[256];
#pragma unroll
    for (int s = 0; s < 2; ++s) {
        int idx = d + s * 256;        // float4 index over 512
        int h = idx >> 6, q = idx & 63;
        ((float4*)at)[idx] =
            ((const float4*)(attn + ((size_t)(bb * 8 + h) * 256 + ii) * 256))[q];
    }
    __syncthreads();
    int h = d >> 5;
    float acc = 0.f;
#pragma unroll 4
    for (int j = 0; j < 256; ++j)
        acc = fmaf(at[h * 256 + j], np_[(bb * 256 + j) * 256 + d], acc);
    xl[d] = acc;
    __syncthreads();
    float acc2 = bias[d];
#pragma unroll 4
    for (int k = 0; k < 256; ++k) acc2 = fmaf(xl[k], Wt[k * 256 + d], acc2);
    out[bi * 256 + d] = acc2;
}

// ---------------------------------------------------------------------------
extern "C" void kernel_launch(void* const* d_in, const int* in_sizes, int n_in,
                              void* d_out, int out_size, void* d_ws, size_t ws_size,
                              hipStream_t stream) {
    (void)in_sizes; (void)n_in; (void)out_size; (void)ws_size;
    const float* nodes = (const float*)d_in[0];
    const float* edges = (const float*)d_in[1];
    const float* W     = (const float*)d_in[2];
    const float* bias  = (const float*)d_in[3];

    float* out  = (float*)d_out;           // (4,256,256) = 262144 floats
    float* attn = out + 262144;            // (4,8,256,256) = 2097152 floats

    float* np_ = (float*)d_ws;             // 262144 floats (node projections)
    float* Wt  = np_ + 262144;             // 65536 floats  (W transposed)

    hipLaunchKernelGGL(k_transpose,   dim3(256),  dim3(256), 0, stream, W, Wt);
    hipLaunchKernelGGL(k_node_proj,   dim3(1024), dim3(256), 0, stream, nodes, Wt, bias, np_);
    hipLaunchKernelGGL(k_edge_scores, dim3(4096), dim3(256), 0, stream, edges, W, bias, np_, attn);
    hipLaunchKernelGGL(k_softmax,     dim3(2048), dim3(256), 0, stream, attn);
    hipLaunchKernelGGL(k_out,         dim3(1024), dim3(256), 0, stream, attn, np_, Wt, bias, out);
}

// Round 2
// 547.426 us; speedup vs baseline: 1.5673x; 1.5673x over previous
//
#include <hip/hip_runtime.h>
#include <math.h>

typedef short short8 __attribute__((ext_vector_type(8)));
typedef float f32x4 __attribute__((ext_vector_type(4)));

__device__ __forceinline__ unsigned short f2bf(float x) {
    unsigned u = __float_as_uint(x);
    u += 0x7FFF + ((u >> 16) & 1);   // round-to-nearest-even
    return (unsigned short)(u >> 16);
}
__device__ __forceinline__ float bf2f(unsigned short h) {
    return __uint_as_float(((unsigned)h) << 16);
}

// ---------------------------------------------------------------------------
// K0: prep — Wt (fp32 transpose) + bf16 hi/lo split of W (row-major d x k)
// ---------------------------------------------------------------------------
__global__ __launch_bounds__(256) void k_prep(const float* __restrict__ W,
                                              float* __restrict__ Wt,
                                              unsigned short* __restrict__ Whi,
                                              unsigned short* __restrict__ Wlo) {
    int d = blockIdx.x, k = threadIdx.x;
    float w = W[d * 256 + k];
    Wt[k * 256 + d] = w;
    unsigned short hi = f2bf(w);
    Whi[d * 256 + k] = hi;
    Wlo[d * 256 + k] = f2bf(w - bf2f(hi));
}

// ---------------------------------------------------------------------------
// K1: node projection, 4-way acc split to break fmaf dep chain
// ---------------------------------------------------------------------------
__global__ __launch_bounds__(256) void k_node_proj(const float* __restrict__ nodes,
                                                   const float* __restrict__ Wt,
                                                   const float* __restrict__ bias,
                                                   float* __restrict__ np_) {
    int row = blockIdx.x;
    int d = threadIdx.x;
    __shared__ float xl[256];
    xl[d] = nodes[row * 256 + d];
    __syncthreads();
    float a0 = 0.f, a1 = 0.f, a2 = 0.f, a3 = 0.f;
#pragma unroll 8
    for (int k = 0; k < 256; k += 4) {
        a0 = fmaf(xl[k],     Wt[(k)     * 256 + d], a0);
        a1 = fmaf(xl[k + 1], Wt[(k + 1) * 256 + d], a1);
        a2 = fmaf(xl[k + 2], Wt[(k + 2) * 256 + d], a2);
        a3 = fmaf(xl[k + 3], Wt[(k + 3) * 256 + d], a3);
    }
    np_[row * 256 + d] = bias[d] + (a0 + a1) + (a2 + a3);
}

// ---------------------------------------------------------------------------
// K2: MFMA edge scores. Block = 64 edges (same b,i; j0..j0+63) x 256 dims.
// Split-bf16: acc = Eh*Wh + Eh*Wl + El*Wh (fp32 accumulate).
// Wave w owns dims [w*64, w*64+64) = heads 2w, 2w+1.
// LDS rows stride 40 bf16 (80B): bank = 20*row%32 -> max 2-way (free).
// ---------------------------------------------------------------------------
#define LDSW 40

__global__ __launch_bounds__(256) void k_edge_mfma(const float* __restrict__ edges,
                                                   const unsigned short* __restrict__ Whi,
                                                   const unsigned short* __restrict__ Wlo,
                                                   const float* __restrict__ bias,
                                                   const float* __restrict__ np_,
                                                   float* __restrict__ attn) {
    __shared__ unsigned short Eh[64 * LDSW], El[64 * LDSW];
    __shared__ unsigned short Wh[256 * LDSW], Wl[256 * LDSW];
    __shared__ float npi[256];
    __shared__ float sc[8][64];

    const int t = threadIdx.x;
    const int w = t >> 6, l = t & 63;
    const int m0 = blockIdx.x * 64;
    const int bb = m0 >> 16, ii = (m0 >> 8) & 255, j0 = m0 & 255;

    if (t < 64) ((float4*)npi)[t] = ((const float4*)(np_ + (size_t)(bb * 256 + ii) * 256))[t];

    f32x4 acc[4][4];
#pragma unroll
    for (int mt = 0; mt < 4; ++mt)
#pragma unroll
        for (int nt = 0; nt < 4; ++nt) acc[mt][nt] = (f32x4){0.f, 0.f, 0.f, 0.f};

    const int er = t >> 2, eo = t & 3;  // E staging: row 0..63, octet 0..3
    const float* egbase = edges + (size_t)(m0 + er) * 256 + eo * 8;
    const int col = l & 15, g = l >> 4;

    for (int kc = 0; kc < 8; ++kc) {
        __syncthreads();
        // ---- stage E (fp32 -> bf16 hi/lo) : 64 rows x 32 k
        {
            float4 v0 = *(const float4*)(egbase + kc * 32);
            float4 v1 = *(const float4*)(egbase + kc * 32 + 4);
            float f[8] = {v0.x, v0.y, v0.z, v0.w, v1.x, v1.y, v1.z, v1.w};
            short8 hi, lo;
#pragma unroll
            for (int q = 0; q < 8; ++q) {
                unsigned short h = f2bf(f[q]);
                hi[q] = (short)h;
                lo[q] = (short)f2bf(f[q] - bf2f(h));
            }
            *(short8*)(Eh + er * LDSW + eo * 8) = hi;
            *(short8*)(El + er * LDSW + eo * 8) = lo;
        }
        // ---- stage W hi/lo : 256 rows x 32 k
#pragma unroll
        for (int s = 0; s < 4; ++s) {
            int idx = t + s * 256;
            int d = idx >> 2, o = idx & 3;
            *(short8*)(Wh + d * LDSW + o * 8) =
                *(const short8*)(Whi + d * 256 + kc * 32 + o * 8);
            *(short8*)(Wl + d * LDSW + o * 8) =
                *(const short8*)(Wlo + d * 256 + kc * 32 + o * 8);
        }
        __syncthreads();
        // ---- MFMA
        short8 Ah[4], Al[4];
#pragma unroll
        for (int mt = 0; mt < 4; ++mt) {
            Ah[mt] = *(const short8*)(Eh + (mt * 16 + col) * LDSW + g * 8);
            Al[mt] = *(const short8*)(El + (mt * 16 + col) * LDSW + g * 8);
        }
#pragma unroll
        for (int nt = 0; nt < 4; ++nt) {
            int nrow = w * 64 + nt * 16 + col;
            short8 Bh = *(const short8*)(Wh + nrow * LDSW + g * 8);
            short8 Bl = *(const short8*)(Wl + nrow * LDSW + g * 8);
#pragma unroll
            for (int mt = 0; mt < 4; ++mt) {
                acc[mt][nt] = __builtin_amdgcn_mfma_f32_16x16x32_bf16(Ah[mt], Bh, acc[mt][nt], 0, 0, 0);
                acc[mt][nt] = __builtin_amdgcn_mfma_f32_16x16x32_bf16(Ah[mt], Bl, acc[mt][nt], 0, 0, 0);
                acc[mt][nt] = __builtin_amdgcn_mfma_f32_16x16x32_bf16(Al[mt], Bh, acc[mt][nt], 0, 0, 0);
            }
        }
    }

    // ---- epilogue: scores for heads 2w, 2w+1
    const float isq = 0.17677669529663687f;  // 1/sqrt(32)
    float bv[4], nv[4];
#pragma unroll
    for (int nt = 0; nt < 4; ++nt) {
        int d = w * 64 + nt * 16 + col;
        bv[nt] = bias[d];
        nv[nt] = npi[d];
    }
#pragma unroll
    for (int mt = 0; mt < 4; ++mt) {
#pragma unroll
        for (int r = 0; r < 4; ++r) {
            int el = mt * 16 + g * 4 + r;
            int j = j0 + el;
            const float* npj = np_ + (size_t)(bb * 256 + j) * 256 + w * 64;
            float p0 = acc[mt][0][r] + bv[0];
            float p1 = acc[mt][1][r] + bv[1];
            float p2 = acc[mt][2][r] + bv[2];
            float p3 = acc[mt][3][r] + bv[3];
            float s0 = (p0 + nv[0]) * (p0 + npj[col]) +
                       (p1 + nv[1]) * (p1 + npj[16 + col]);
            float s1 = (p2 + nv[2]) * (p2 + npj[32 + col]) +
                       (p3 + nv[3]) * (p3 + npj[48 + col]);
#pragma unroll
            for (int m = 1; m < 16; m <<= 1) {
                s0 += __shfl_xor(s0, m, 64);
                s1 += __shfl_xor(s1, m, 64);
            }
            if (col == 0) {
                sc[2 * w][el]     = 10.f * tanhf(s0 * isq);
                sc[2 * w + 1][el] = 10.f * tanhf(s1 * isq);
            }
        }
    }
    __syncthreads();
    if (t < 128) {
        int h = t >> 4, q = t & 15;
        float4 v = *(float4*)&sc[h][q * 4];
        *(float4*)(attn + (((size_t)(bb * 8 + h) * 256 + ii) << 8) + j0 + q * 4) = v;
    }
}

// ---------------------------------------------------------------------------
// K3: softmax over j (rows of 256), one wave per row
// ---------------------------------------------------------------------------
__global__ __launch_bounds__(256) void k_softmax(float* __restrict__ attn) {
    int row = (blockIdx.x * 256 + threadIdx.x) >> 6;
    int lane = threadIdx.x & 63;
    float4* rowp = (float4*)(attn + (size_t)row * 256);
    float4 v = rowp[lane];
    float m = fmaxf(fmaxf(v.x, v.y), fmaxf(v.z, v.w));
#pragma unroll
    for (int s = 1; s < 64; s <<= 1) m = fmaxf(m, __shfl_xor(m, s, 64));
    v.x = expf(v.x - m); v.y = expf(v.y - m);
    v.z = expf(v.z - m); v.w = expf(v.w - m);
    float sum = v.x + v.y + v.z + v.w;
#pragma unroll
    for (int s = 1; s < 64; s <<= 1) sum += __shfl_xor(sum, s, 64);
    float inv = 1.f / sum;
    v.x *= inv; v.y *= inv; v.z *= inv; v.w *= inv;
    rowp[lane] = v;
}

// ---------------------------------------------------------------------------
// K4: out = proj(attn @ np), 4-way acc splits
// ---------------------------------------------------------------------------
__global__ __launch_bounds__(256) void k_out(const float* __restrict__ attn,
                                             const float* __restrict__ np_,
                                             const float* __restrict__ Wt,
                                             const float* __restrict__ bias,
                                             float* __restrict__ out) {
    int bi = blockIdx.x;
    int bb = bi >> 8, ii = bi & 255;
    int d = threadIdx.x;
    __shared__ float at[8 * 256];
    __shared__ float xl[256];
#pragma unroll
    for (int s = 0; s < 2; ++s) {
        int idx = d + s * 256;
        int h = idx >> 6, q = idx & 63;
        ((float4*)at)[idx] =
            ((const float4*)(attn + ((size_t)(bb * 8 + h) * 256 + ii) * 256))[q];
    }
    __syncthreads();
    int h = d >> 5;
    const float* npb = np_ + (size_t)bb * 65536 + d;
    const float* ath = at + h * 256;
    float a0 = 0.f, a1 = 0.f, a2 = 0.f, a3 = 0.f;
#pragma unroll 4
    for (int j = 0; j < 256; j += 4) {
        a0 = fmaf(ath[j],     npb[(size_t)(j)     * 256], a0);
        a1 = fmaf(ath[j + 1], npb[(size_t)(j + 1) * 256], a1);
        a2 = fmaf(ath[j + 2], npb[(size_t)(j + 2) * 256], a2);
        a3 = fmaf(ath[j + 3], npb[(size_t)(j + 3) * 256], a3);
    }
    xl[d] = (a0 + a1) + (a2 + a3);
    __syncthreads();
    float c0 = bias[d], c1 = 0.f, c2 = 0.f, c3 = 0.f;
#pragma unroll 4
    for (int k = 0; k < 256; k += 4) {
        c0 = fmaf(xl[k],     Wt[(k)     * 256 + d], c0);
        c1 = fmaf(xl[k + 1], Wt[(k + 1) * 256 + d], c1);
        c2 = fmaf(xl[k + 2], Wt[(k + 2) * 256 + d], c2);
        c3 = fmaf(xl[k + 3], Wt[(k + 3) * 256 + d], c3);
    }
    out[bi * 256 + d] = (c0 + c1) + (c2 + c3);
}

// ---------------------------------------------------------------------------
extern "C" void kernel_launch(void* const* d_in, const int* in_sizes, int n_in,
                              void* d_out, int out_size, void* d_ws, size_t ws_size,
                              hipStream_t stream) {
    (void)in_sizes; (void)n_in; (void)out_size; (void)ws_size;
    const float* nodes = (const float*)d_in[0];
    const float* edges = (const float*)d_in[1];
    const float* W     = (const float*)d_in[2];
    const float* bias  = (const float*)d_in[3];

    float* out  = (float*)d_out;            // (4,256,256)
    float* attn = out + 262144;             // (4,8,256,256)

    float* np_ = (float*)d_ws;              // 262144 floats
    float* Wt  = np_ + 262144;              // 65536 floats
    unsigned short* Whi = (unsigned short*)(Wt + 65536);  // 65536 bf16
    unsigned short* Wlo = Whi + 65536;                    // 65536 bf16

    hipLaunchKernelGGL(k_prep,      dim3(256),  dim3(256), 0, stream, W, Wt, Whi, Wlo);
    hipLaunchKernelGGL(k_node_proj, dim3(1024), dim3(256), 0, stream, nodes, Wt, bias, np_);
    hipLaunchKernelGGL(k_edge_mfma, dim3(4096), dim3(256), 0, stream, edges, Whi, Wlo, bias, np_, attn);
    hipLaunchKernelGGL(k_softmax,   dim3(2048), dim3(256), 0, stream, attn);
    hipLaunchKernelGGL(k_out,       dim3(1024), dim3(256), 0, stream, attn, np_, Wt, bias, out);
}

// Round 3
// 529.556 us; speedup vs baseline: 1.6201x; 1.0337x over previous
//
#include <hip/hip_runtime.h>
#include <hip/hip_bf16.h>
#include <math.h>

typedef short short8 __attribute__((ext_vector_type(8)));
typedef float f32x4 __attribute__((ext_vector_type(4)));

__device__ __forceinline__ unsigned short f2bf(float x) {
    unsigned u = __float_as_uint(x);
    u += 0x7FFF + ((u >> 16) & 1);   // RNE
    return (unsigned short)(u >> 16);
}
__device__ __forceinline__ float bf2f(unsigned short h) {
    return __uint_as_float(((unsigned)h) << 16);
}

// packed hi/lo split of 2 floats (uses v_cvt_pk_bf16_f32 via HIP API)
__device__ __forceinline__ void cvt2(float f0, float f1,
                                     unsigned short& h0, unsigned short& h1,
                                     unsigned short& l0, unsigned short& l1) {
    __hip_bfloat162 h = __float22bfloat162_rn(float2{f0, f1});
    unsigned hu = *(unsigned*)&h;
    h0 = (unsigned short)(hu & 0xFFFFu);
    h1 = (unsigned short)(hu >> 16);
    float r0 = f0 - __uint_as_float((hu & 0xFFFFu) << 16);
    float r1 = f1 - __uint_as_float(hu & 0xFFFF0000u);
    __hip_bfloat162 lo = __float22bfloat162_rn(float2{r0, r1});
    unsigned lu = *(unsigned*)&lo;
    l0 = (unsigned short)(lu & 0xFFFFu);
    l1 = (unsigned short)(lu >> 16);
}

__device__ __forceinline__ float tanh10(float y) {
    // 10*tanh(y) = 10*(e^{2y}-1)/(e^{2y}+1), |y| small enough here (no overflow)
    float e = __expf(2.f * y);
    return 10.f * (e - 1.f) / (e + 1.f);
}

#define GLDS16(gp, lp)                                                        \
    __builtin_amdgcn_global_load_lds(                                         \
        (const __attribute__((address_space(1))) void*)(gp),                  \
        (__attribute__((address_space(3))) void*)(lp), 16, 0, 0)

// ---------------------------------------------------------------------------
// K0: prep — Wt (fp32 transpose) + bf16 hi/lo split of W (row-major d x k)
// ---------------------------------------------------------------------------
__global__ __launch_bounds__(256) void k_prep(const float* __restrict__ W,
                                              float* __restrict__ Wt,
                                              unsigned short* __restrict__ Whi,
                                              unsigned short* __restrict__ Wlo) {
    int d = blockIdx.x, k = threadIdx.x;
    float w = W[d * 256 + k];
    Wt[k * 256 + d] = w;
    unsigned short hi = f2bf(w);
    Whi[d * 256 + k] = hi;
    Wlo[d * 256 + k] = f2bf(w - bf2f(hi));
}

// ---------------------------------------------------------------------------
// K1: node projection, 8-way acc split
// ---------------------------------------------------------------------------
__global__ __launch_bounds__(256) void k_node_proj(const float* __restrict__ nodes,
                                                   const float* __restrict__ Wt,
                                                   const float* __restrict__ bias,
                                                   float* __restrict__ np_) {
    int row = blockIdx.x;
    int d = threadIdx.x;
    __shared__ float xl[256];
    xl[d] = nodes[row * 256 + d];
    __syncthreads();
    float a[8] = {0.f, 0.f, 0.f, 0.f, 0.f, 0.f, 0.f, 0.f};
#pragma unroll 4
    for (int k = 0; k < 256; k += 8) {
#pragma unroll
        for (int q = 0; q < 8; ++q)
            a[q] = fmaf(xl[k + q], Wt[(k + q) * 256 + d], a[q]);
    }
    np_[row * 256 + d] =
        bias[d] + ((a[0] + a[1]) + (a[2] + a[3])) + ((a[4] + a[5]) + (a[6] + a[7]));
}

// ---------------------------------------------------------------------------
// K2: MFMA edge scores, m97-style.
// Block = 128 edges (same b,i; consecutive j) x 128 dims (4 whole heads).
// grid.x = 2048 edge-tiles * 2 dim-halves = 4096.
// LDS rows: 32 shorts (64B), unpadded (required by global_load_lds layout).
// W staged async via global_load_lds (pre-split bf16 hi/lo).
// E staged via register prefetch + packed bf16 split.
// acc = Eh*Wh + Eh*Wl + El*Wh  (fp32 acc; dropped El*Wl ~2^-17 rel).
// ---------------------------------------------------------------------------
__global__ __launch_bounds__(256) void k_edge_mfma(const float* __restrict__ edges,
                                                   const unsigned short* __restrict__ Whi,
                                                   const unsigned short* __restrict__ Wlo,
                                                   const float* __restrict__ bias,
                                                   const float* __restrict__ np_,
                                                   float* __restrict__ attn) {
    __shared__ unsigned short Eh[128 * 32], El[128 * 32];  // 8 KB each
    __shared__ unsigned short Wh[128 * 32], Wl[128 * 32];  // 8 KB each
    __shared__ float npi[128];
    __shared__ float sc[4][128];

    const int t = threadIdx.x;
    const int w = t >> 6, l = t & 63;
    const int tile = blockIdx.x >> 1;
    const int half = blockIdx.x & 1;
    const int m0 = tile * 128;             // first edge flat index
    const int bb = m0 >> 16;
    const int ii = (m0 >> 8) & 255;
    const int j0 = m0 & 255;               // 0 or 128
    const int n0 = half * 128;             // dim offset (heads 4*half..4*half+3)

    if (t < 32)
        ((float4*)npi)[t] = ((const float4*)(np_ + (size_t)(bb * 256 + ii) * 256 + n0))[t];

    f32x4 acc[4][4];
#pragma unroll
    for (int mt = 0; mt < 4; ++mt)
#pragma unroll
        for (int nt = 0; nt < 4; ++nt) acc[mt][nt] = (f32x4){0.f, 0.f, 0.f, 0.f};

    // E staging mapping: thread t -> row r=t>>1 (0..127), 16-float half hk=t&1
    const int er = t >> 1, ehk = t & 1;
    const float* esrc = edges + (size_t)(m0 + er) * 256 + ehk * 16;

    // W async staging mapping: wave w, inst s in {0,1}: rows base = w*32+s*16
    // lane l: row = base + (l>>2), 16B-quarter q = l&3
    const int wrow = (l >> 2), wq = l & 3;

    // fragment read mapping
    const int col = l & 15, g = l >> 4;
    const int wm = (w & 1) * 64, wn = (w >> 1) * 64;

    float4 ecur[4], enext[4];
#pragma unroll
    for (int q = 0; q < 4; ++q) ecur[q] = *(const float4*)(esrc + q * 4);

    for (int kc = 0; kc < 8; ++kc) {
        // ---- async W hi/lo -> LDS (no VGPR roundtrip)
#pragma unroll
        for (int s = 0; s < 2; ++s) {
            int base = w * 32 + s * 16;
            const unsigned short* gh =
                Whi + (size_t)(n0 + base + wrow) * 256 + kc * 32 + wq * 8;
            const unsigned short* gl =
                Wlo + (size_t)(n0 + base + wrow) * 256 + kc * 32 + wq * 8;
            GLDS16(gh, Wh + base * 32);
            GLDS16(gl, Wl + base * 32);
        }
        // ---- convert E regs (chunk kc) -> LDS
        {
            unsigned short hi[16], lo[16];
#pragma unroll
            for (int q = 0; q < 4; ++q) {
                cvt2(ecur[q].x, ecur[q].y, hi[q * 4 + 0], hi[q * 4 + 1],
                     lo[q * 4 + 0], lo[q * 4 + 1]);
                cvt2(ecur[q].z, ecur[q].w, hi[q * 4 + 2], hi[q * 4 + 3],
                     lo[q * 4 + 2], lo[q * 4 + 3]);
            }
            *(short8*)(Eh + er * 32 + ehk * 16)     = *(short8*)&hi[0];
            *(short8*)(Eh + er * 32 + ehk * 16 + 8) = *(short8*)&hi[8];
            *(short8*)(El + er * 32 + ehk * 16)     = *(short8*)&lo[0];
            *(short8*)(El + er * 32 + ehk * 16 + 8) = *(short8*)&lo[8];
        }
        // ---- prefetch E regs for chunk kc+1
        if (kc < 7) {
#pragma unroll
            for (int q = 0; q < 4; ++q)
                enext[q] = *(const float4*)(esrc + (kc + 1) * 32 + q * 4);
        }
        __syncthreads();
        // ---- MFMA
        short8 Ah[4], Al[4];
#pragma unroll
        for (int mt = 0; mt < 4; ++mt) {
            Ah[mt] = *(const short8*)(Eh + (wm + mt * 16 + col) * 32 + g * 8);
            Al[mt] = *(const short8*)(El + (wm + mt * 16 + col) * 32 + g * 8);
        }
#pragma unroll
        for (int nt = 0; nt < 4; ++nt) {
            short8 Bh = *(const short8*)(Wh + (wn + nt * 16 + col) * 32 + g * 8);
            short8 Bl = *(const short8*)(Wl + (wn + nt * 16 + col) * 32 + g * 8);
#pragma unroll
            for (int mt = 0; mt < 4; ++mt) {
                acc[mt][nt] = __builtin_amdgcn_mfma_f32_16x16x32_bf16(Ah[mt], Bh, acc[mt][nt], 0, 0, 0);
                acc[mt][nt] = __builtin_amdgcn_mfma_f32_16x16x32_bf16(Ah[mt], Bl, acc[mt][nt], 0, 0, 0);
                acc[mt][nt] = __builtin_amdgcn_mfma_f32_16x16x32_bf16(Al[mt], Bh, acc[mt][nt], 0, 0, 0);
            }
        }
        __syncthreads();
#pragma unroll
        for (int q = 0; q < 4; ++q) ecur[q] = enext[q];
    }

    // ---- epilogue: scores for the 2 heads this wave owns
    const float isq = 0.17677669529663687f;  // 1/sqrt(32)
    float bv[4], nv[4];
#pragma unroll
    for (int nt = 0; nt < 4; ++nt) {
        int dl = wn + nt * 16 + col;
        bv[nt] = bias[n0 + dl];
        nv[nt] = npi[dl];
    }
    const int hl0 = (w >> 1) * 2;  // block-local head pair
#pragma unroll
    for (int mt = 0; mt < 4; ++mt) {
#pragma unroll
        for (int r = 0; r < 4; ++r) {
            int el = wm + mt * 16 + g * 4 + r;   // 0..127 within tile
            int j = j0 + el;
            const float* npj = np_ + (size_t)(bb * 256 + j) * 256 + n0 + wn;
            float p0 = acc[mt][0][r] + bv[0];
            float p1 = acc[mt][1][r] + bv[1];
            float p2 = acc[mt][2][r] + bv[2];
            float p3 = acc[mt][3][r] + bv[3];
            float s0 = (p0 + nv[0]) * (p0 + npj[col]) +
                       (p1 + nv[1]) * (p1 + npj[16 + col]);
            float s1 = (p2 + nv[2]) * (p2 + npj[32 + col]) +
                       (p3 + nv[3]) * (p3 + npj[48 + col]);
#pragma unroll
            for (int m = 1; m < 16; m <<= 1) {
                s0 += __shfl_xor(s0, m, 64);
                s1 += __shfl_xor(s1, m, 64);
            }
            if (col == 0) {
                sc[hl0][el]     = tanh10(s0 * isq);
                sc[hl0 + 1][el] = tanh10(s1 * isq);
            }
        }
    }
    __syncthreads();
    if (t < 128) {
        int hl = t >> 5, q = t & 31;
        float4 v = *(float4*)&sc[hl][q * 4];
        *(float4*)(attn + (((size_t)(bb * 8 + half * 4 + hl) * 256 + ii) << 8) + j0 + q * 4) = v;
    }
}

// ---------------------------------------------------------------------------
// K3: softmax over j (rows of 256), one wave per row
// ---------------------------------------------------------------------------
__global__ __launch_bounds__(256) void k_softmax(float* __restrict__ attn) {
    int row = (blockIdx.x * 256 + threadIdx.x) >> 6;
    int lane = threadIdx.x & 63;
    float4* rowp = (float4*)(attn + (size_t)row * 256);
    float4 v = rowp[lane];
    float m = fmaxf(fmaxf(v.x, v.y), fmaxf(v.z, v.w));
#pragma unroll
    for (int s = 1; s < 64; s <<= 1) m = fmaxf(m, __shfl_xor(m, s, 64));
    v.x = __expf(v.x - m); v.y = __expf(v.y - m);
    v.z = __expf(v.z - m); v.w = __expf(v.w - m);
    float sum = v.x + v.y + v.z + v.w;
#pragma unroll
    for (int s = 1; s < 64; s <<= 1) sum += __shfl_xor(sum, s, 64);
    float inv = 1.f / sum;
    v.x *= inv; v.y *= inv; v.z *= inv; v.w *= inv;
    rowp[lane] = v;
}

// ---------------------------------------------------------------------------
// K4: out = proj(attn @ np), 8-way acc splits
// ---------------------------------------------------------------------------
__global__ __launch_bounds__(256) void k_out(const float* __restrict__ attn,
                                             const float* __restrict__ np_,
                                             const float* __restrict__ Wt,
                                             const float* __restrict__ bias,
                                             float* __restrict__ out) {
    int bi = blockIdx.x;
    int bb = bi >> 8, ii = bi & 255;
    int d = threadIdx.x;
    __shared__ float at[8 * 256];
    __shared__ float xl[256];
#pragma unroll
    for (int s = 0; s < 2; ++s) {
        int idx = d + s * 256;
        int h = idx >> 6, q = idx & 63;
        ((float4*)at)[idx] =
            ((const float4*)(attn + ((size_t)(bb * 8 + h) * 256 + ii) * 256))[q];
    }
    __syncthreads();
    int h = d >> 5;
    const float* npb = np_ + (size_t)bb * 65536 + d;
    const float* ath = at + h * 256;
    float a[8] = {0.f, 0.f, 0.f, 0.f, 0.f, 0.f, 0.f, 0.f};
#pragma unroll 2
    for (int j = 0; j < 256; j += 8) {
#pragma unroll
        for (int q = 0; q < 8; ++q)
            a[q] = fmaf(ath[j + q], npb[(size_t)(j + q) * 256], a[q]);
    }
    xl[d] = ((a[0] + a[1]) + (a[2] + a[3])) + ((a[4] + a[5]) + (a[6] + a[7]));
    __syncthreads();
    float c[8] = {bias[d], 0.f, 0.f, 0.f, 0.f, 0.f, 0.f, 0.f};
#pragma unroll 2
    for (int k = 0; k < 256; k += 8) {
#pragma unroll
        for (int q = 0; q < 8; ++q)
            c[q] = fmaf(xl[k + q], Wt[(k + q) * 256 + d], c[q]);
    }
    out[bi * 256 + d] =
        ((c[0] + c[1]) + (c[2] + c[3])) + ((c[4] + c[5]) + (c[6] + c[7]));
}

// ---------------------------------------------------------------------------
extern "C" void kernel_launch(void* const* d_in, const int* in_sizes, int n_in,
                              void* d_out, int out_size, void* d_ws, size_t ws_size,
                              hipStream_t stream) {
    (void)in_sizes; (void)n_in; (void)out_size; (void)ws_size;
    const float* nodes = (const float*)d_in[0];
    const float* edges = (const float*)d_in[1];
    const float* W     = (const float*)d_in[2];
    const float* bias  = (const float*)d_in[3];

    float* out  = (float*)d_out;            // (4,256,256)
    float* attn = out + 262144;             // (4,8,256,256)

    float* np_ = (float*)d_ws;              // 262144 floats
    float* Wt  = np_ + 262144;              // 65536 floats
    unsigned short* Whi = (unsigned short*)(Wt + 65536);  // 65536 bf16
    unsigned short* Wlo = Whi + 65536;                    // 65536 bf16

    hipLaunchKernelGGL(k_prep,      dim3(256),  dim3(256), 0, stream, W, Wt, Whi, Wlo);
    hipLaunchKernelGGL(k_node_proj, dim3(1024), dim3(256), 0, stream, nodes, Wt, bias, np_);
    hipLaunchKernelGGL(k_edge_mfma, dim3(4096), dim3(256), 0, stream, edges, Whi, Wlo, bias, np_, attn);
    hipLaunchKernelGGL(k_softmax,   dim3(2048), dim3(256), 0, stream, attn);
    hipLaunchKernelGGL(k_out,       dim3(1024), dim3(256), 0, stream, attn, np_, Wt, bias, out);
}